// Round 13
// baseline (470.984 us; speedup 1.0000x reference)
//
#include <hip/hip_runtime.h>
#include <math.h>

constexpr int B = 64;
constexpr int L = 4096;
constexpr int C = 256;
constexpr int H = 32;

constexpr int NBLK = 1024;        // 4 blocks/CU x 256 CU — co-resident by launch_bounds
constexpr int SEGS = NBLK / B;    // 16 segments per batch
constexpr int SROWS = L / SEGS;   // 256 rows per segment (256 KB)

typedef float v4f __attribute__((ext_vector_type(4)));

// Device-scope software grid barrier. Requires all blocks co-resident
// (guaranteed: __launch_bounds__(256,4) -> <=128 VGPR -> 4 blocks/CU -> 1024
// slots = grid size). atomicAdd is device-scope on CDNA (guide G12);
// __threadfence() provides agent release/acquire (L2 writeback+invalidate).
__device__ __forceinline__ void grid_barrier(unsigned int* cnt, unsigned int target) {
    __syncthreads();
    if (threadIdx.x == 0) {
        __threadfence();                        // release prior writes
        atomicAdd(cnt, 1u);
        while (atomicAdd(cnt, 0u) < target) {   // device-coherent read
            __builtin_amdgcn_s_sleep(2);
        }
    }
    __syncthreads();
    __threadfence();                            // acquire: drop stale lines
}

__global__ __launch_bounds__(256, 4) void se_fused(
        const float* __restrict__ in,
        const float* __restrict__ w1, const float* __restrict__ b1,
        const float* __restrict__ w2, const float* __restrict__ b2,
        v4f* __restrict__ out,
        float* __restrict__ partial, float* __restrict__ g,
        unsigned int* __restrict__ bar) {
    const int j = blockIdx.x;
    const int b = j >> 4;        // j / SEGS
    const int seg = j & 15;      // j % SEGS
    const int t = threadIdx.x;
    const int c4 = t & 63;
    const int r0 = t >> 6;       // 0..3

    const v4f* base = reinterpret_cast<const v4f*>(in)
                    + (size_t)b * L * (C / 4) + (size_t)seg * SROWS * (C / 4);

    // ---- Phase 1: reduce this block's 256 rows (plain loads -> MALL-warm) ----
    v4f acc = (v4f)(0.f);
    #pragma unroll
    for (int grp = 0; grp < 8; ++grp) {
        const size_t i0 = (size_t)(r0 + grp * 32) * (C / 4) + c4;
        v4f v[8];
        #pragma unroll
        for (int k = 0; k < 8; ++k) v[k] = base[i0 + (size_t)k * 4 * (C / 4)];
        #pragma unroll
        for (int k = 0; k < 8; ++k) acc += v[k];
    }
    __shared__ v4f red[4][C / 4];
    red[r0][c4] = acc;
    __syncthreads();
    if (r0 == 0) {
        v4f s = red[0][c4] + red[1][c4] + red[2][c4] + red[3][c4];
        reinterpret_cast<v4f*>(partial + (size_t)j * C)[c4] = s;
    }

    grid_barrier(&bar[0], NBLK);

    // ---- Phase 2: blocks 0..63 compute the gate row for batch = j ----
    if (j < B) {
        __shared__ float sm[C];
        __shared__ float ep[8][H];
        __shared__ float em[H];

        float a = 0.f;
        const float* p = partial + (size_t)j * SEGS * C + t;
        #pragma unroll
        for (int k = 0; k < SEGS; ++k) a += p[(size_t)k * C];
        sm[t] = a * (1.0f / (float)L);
        __syncthreads();

        {   // w1: all 256 threads — thread t does h = t&31 over a 32-c slice
            const int h = t & 31, cs = t >> 5;
            float a1 = 0.f;
            #pragma unroll 8
            for (int c = cs * 32; c < cs * 32 + 32; ++c) a1 += sm[c] * w1[c * H + h];
            ep[cs][h] = a1;
        }
        __syncthreads();
        if (t < H) {
            float a1 = b1[t];
            #pragma unroll
            for (int k = 0; k < 8; ++k) a1 += ep[k][t];
            em[t] = fmaxf(a1, 0.0f);
        }
        __syncthreads();

        float a2 = b2[t];
        #pragma unroll
        for (int h = 0; h < H; ++h) a2 += em[h] * w2[h * C + t];
        g[j * C + t] = 1.0f / (1.0f + expf(-a2));
    }

    grid_barrier(&bar[1], NBLK);

    // ---- Phase 3: scale this block's rows (nt loads + nt stores, 8-deep) ----
    const v4f gv = reinterpret_cast<const v4f*>(g)[b * (C / 4) + c4];
    v4f* outb = out + (size_t)b * L * (C / 4) + (size_t)seg * SROWS * (C / 4);

    #pragma unroll
    for (int grp = 0; grp < 8; ++grp) {
        const size_t i0 = (size_t)(r0 + grp * 32) * (C / 4) + c4;
        v4f v[8];
        #pragma unroll
        for (int k = 0; k < 8; ++k)
            v[k] = __builtin_nontemporal_load(&base[i0 + (size_t)k * 4 * (C / 4)]);
        #pragma unroll
        for (int k = 0; k < 8; ++k)
            __builtin_nontemporal_store(v[k] * gv, &outb[i0 + (size_t)k * 4 * (C / 4)]);
    }
}

extern "C" void kernel_launch(void* const* d_in, const int* in_sizes, int n_in,
                              void* d_out, int out_size, void* d_ws, size_t ws_size,
                              hipStream_t stream) {
    const float* in = (const float*)d_in[0];
    const float* w1 = (const float*)d_in[1];
    const float* b1 = (const float*)d_in[2];
    const float* w2 = (const float*)d_in[3];
    const float* b2 = (const float*)d_in[4];
    v4f* out = (v4f*)d_out;

    float* partial = (float*)d_ws;                   // NBLK*C floats = 1 MB
    float* g = partial + (size_t)NBLK * C;           // B*C floats = 64 KB
    unsigned int* bar = (unsigned int*)(g + B * C);  // 2 counters

    hipMemsetAsync(bar, 0, 2 * sizeof(unsigned int), stream);
    se_fused<<<NBLK, 256, 0, stream>>>(in, w1, b1, w2, b2, out, partial, g, bar);
}